// Round 4
// baseline (498.570 us; speedup 1.0000x reference)
//
#include <hip/hip_runtime.h>
#include <hip/hip_bf16.h>

// Network: bidirectional LSTM (T=256, B=1024, E=300, H=50) + small MLP head.
// h_bw[0] needs only ONE backward step (zero init state); x@Wx hoisted into
// per-VOCAB precompute P = E @ W_fw[0:300,:] computed with split-bf16 MFMA.

#define VOCAB 50000
#define EMB   300
#define HID   50
#define GATES 200          // 4*H
#define BATCH 1024
#define TT    256          // 2*MAX_LEN
#define NPAD  208          // 13 * 16
#define KPAD  320          // 10 * 32
#define BN_SCALE 0.9995003746877732f   // 1/sqrt(1.001)

typedef short bf16x8 __attribute__((ext_vector_type(8)));
typedef float f32x4  __attribute__((ext_vector_type(4)));

__device__ __forceinline__ float sigm(float x) {
    return 1.0f / (1.0f + __expf(-x));
}
__device__ __forceinline__ float tanh_f(float x) {
    return 1.0f - 2.0f / (__expf(2.0f * x) + 1.0f);   // saturates correctly
}
__device__ __forceinline__ unsigned short f32_to_bf16(float x) {
    unsigned int u = __float_as_uint(x);
    u += 0x7fffu + ((u >> 16) & 1u);   // round-to-nearest-even (finite inputs)
    return (unsigned short)(u >> 16);
}
__device__ __forceinline__ float bf16_to_f32(unsigned short h) {
    return __uint_as_float(((unsigned int)h) << 16);
}

// ---------------------------------------------------------------------------
// K0: split Wx = W_fw[0:300,:] into bf16 hi/lo, TRANSPOSED + zero-padded to
// [NPAD][KPAD] so B-fragments are contiguous 16B loads. 66560 elems, tiny.
// ---------------------------------------------------------------------------
__global__ __launch_bounds__(256) void split_w(const float* __restrict__ Wfw,
                                               unsigned short* __restrict__ WhT,
                                               unsigned short* __restrict__ WlT) {
    const int idx = blockIdx.x * 256 + threadIdx.x;
    if (idx >= NPAD * KPAD) return;
    const int n = idx / KPAD;
    const int k = idx - n * KPAD;
    float v = (n < GATES && k < EMB) ? Wfw[k * GATES + n] : 0.0f;
    const unsigned short hb = f32_to_bf16(v);
    const unsigned short lb = f32_to_bf16(v - bf16_to_f32(hb));
    WhT[idx] = hb;
    WlT[idx] = lb;
}

// ---------------------------------------------------------------------------
// K1: P = E @ Wx via 16x16x32 bf16 MFMA, error-compensated split:
//     E*W ~= Eh*Wh + El*Wh + Eh*Wl  (f32 accumulate; dropped El*Wl ~ 1e-5).
// Block = 64 vocab rows, 4 waves; wave owns 16 rows x 208 cols (13 frags),
// K-loop 10 steps of 32 (E padded by guard, W padded in split_w).
// C/D layout: col = lane&15, row = (lane>>4)*4 + reg   [measured m89/m91]
// ---------------------------------------------------------------------------
__global__ __launch_bounds__(256) void vocab_proj_mfma(const float* __restrict__ E,
                                                       const unsigned short* __restrict__ WhT,
                                                       const unsigned short* __restrict__ WlT,
                                                       float* __restrict__ P) {
    const int w  = threadIdx.x >> 6;
    const int l  = threadIdx.x & 63;
    const int lr = l & 15;        // row-in-tile (A) / col-in-frag (B, C)
    const int lg = l >> 4;        // k-group (A,B) / row-group (C)

    const int row    = blockIdx.x * 64 + w * 16 + lr;
    const int rclamp = (row < VOCAB) ? row : (VOCAB - 1);
    const float* Erow = E + (size_t)rclamp * EMB;

    f32x4 acc[13];
#pragma unroll
    for (int f = 0; f < 13; ++f) acc[f] = (f32x4){0.f, 0.f, 0.f, 0.f};

    for (int ks = 0; ks < 10; ++ks) {
        const int k0 = ks * 32 + lg * 8;
        float av[8];
        if (ks < 9) {
            const float4 a0 = *reinterpret_cast<const float4*>(Erow + k0);
            const float4 a1 = *reinterpret_cast<const float4*>(Erow + k0 + 4);
            av[0] = a0.x; av[1] = a0.y; av[2] = a0.z; av[3] = a0.w;
            av[4] = a1.x; av[5] = a1.y; av[6] = a1.z; av[7] = a1.w;
        } else {
#pragma unroll
            for (int j = 0; j < 8; ++j) {
                const int kk = k0 + j;
                av[j] = (kk < EMB) ? Erow[kk] : 0.0f;
            }
        }
        bf16x8 ah, al;
#pragma unroll
        for (int j = 0; j < 8; ++j) {
            const unsigned short hb = f32_to_bf16(av[j]);
            ah[j] = (short)hb;
            al[j] = (short)f32_to_bf16(av[j] - bf16_to_f32(hb));
        }

#pragma unroll
        for (int f = 0; f < 13; ++f) {
            const int n = f * 16 + lr;
            const size_t boff = (size_t)n * KPAD + k0;
            const bf16x8 bh = *reinterpret_cast<const bf16x8*>(WhT + boff);
            const bf16x8 bl = *reinterpret_cast<const bf16x8*>(WlT + boff);
            acc[f] = __builtin_amdgcn_mfma_f32_16x16x32_bf16(ah, bh, acc[f], 0, 0, 0);
            acc[f] = __builtin_amdgcn_mfma_f32_16x16x32_bf16(al, bh, acc[f], 0, 0, 0);
            acc[f] = __builtin_amdgcn_mfma_f32_16x16x32_bf16(ah, bl, acc[f], 0, 0, 0);
        }
    }

    const int orow0 = blockIdx.x * 64 + w * 16 + lg * 4;
#pragma unroll
    for (int f = 0; f < 13; ++f) {
        const int col = f * 16 + lr;
        if (col < GATES) {
#pragma unroll
            for (int r = 0; r < 4; ++r) {
                const int orow = orow0 + r;
                if (orow < VOCAB) P[(size_t)orow * GATES + col] = acc[f][r];
            }
        }
    }
}

// ---------------------------------------------------------------------------
// K2: forward LSTM. 2 waves per batch row, split along K (not gates):
// wave w accumulates k in [25w, 25w+25) for ALL FOUR gate columns of its
// lane's unit (100 weight VGPRs, forced resident by __launch_bounds__(128,1)).
// Partial sums exchanged once/step (float4 write + float4 read, parity
// double-buffer, one raw s_barrier with lgkmcnt-only drain); both waves then
// redundantly compute activations and c,h -> no second exchange, and only 25
// readlane broadcasts per step. P-row prefetch issued a step ahead stays in
// flight across the barrier (no vmcnt drain).
// ---------------------------------------------------------------------------
__global__ __launch_bounds__(128, 1) void lstm_fw(const int* __restrict__ x1,
                                                  const int* __restrict__ x2,
                                                  const float* __restrict__ P,
                                                  const float* __restrict__ Wfw,
                                                  const float* __restrict__ bfw,
                                                  float* __restrict__ feat) {
    const int b = blockIdx.x;
    const int w = threadIdx.x >> 6;      // k-half owner
    const int l = threadIdx.x & 63;
    const int u = (l < HID) ? l : (HID - 1);   // clamp for loads
    const bool act_lane = (l < HID);

    __shared__ int    stok[TT];
    __shared__ float4 ex[2][2][HID];     // [parity][wave][unit] partial gates

    stok[threadIdx.x]       = x1[b * 128 + threadIdx.x];
    stok[128 + threadIdx.x] = x2[b * 128 + threadIdx.x];

    // weights for k-range [25w, 25w+25), all 4 gate columns of unit u
    float wi[25], wj[25], wf[25], wo[25];
#pragma unroll
    for (int k = 0; k < 25; ++k) {
        const float* rowp = Wfw + (size_t)(EMB + 25 * w + k) * GATES;
        wi[k] = rowp[u];
        wj[k] = rowp[u + 50];
        wf[k] = rowp[u + 100];
        wo[k] = rowp[u + 150];
    }
    const float bi0 = bfw[u];
    const float bj0 = bfw[u + 50];
    const float bf0 = bfw[u + 100] + 1.0f;   // forget_bias folded in
    const float bo0 = bfw[u + 150];

    float c = 0.0f, h = 0.0f;
    __syncthreads();   // tokens staged (once)

    int tok = stok[0];
    const float* pr0 = P + (size_t)tok * GATES + u;
    float pi = pr0[0], pj = pr0[50], pf = pr0[100], po = pr0[150];
    int tokn = stok[1];

    for (int t = 0; t < TT; ++t) {
        const float cpi = pi, cpj = pj, cpf = pf, cpo = po;
        // prefetch step t+1 (stays in flight across the s_barrier)
        {
            const float* pn = P + (size_t)tokn * GATES + u;
            pi = pn[0]; pj = pn[50]; pf = pn[100]; po = pn[150];
        }
        tokn = stok[(t + 2 < TT) ? (t + 2) : (TT - 1)];

        float gi = 0.0f, gj = 0.0f, gf = 0.0f, go = 0.0f;
#pragma unroll
        for (int k = 0; k < 25; ++k) {
            const float hk = __uint_as_float(
                __builtin_amdgcn_readlane(__float_as_uint(h), 25 * w + k));
            gi = fmaf(wi[k], hk, gi);
            gj = fmaf(wj[k], hk, gj);
            gf = fmaf(wf[k], hk, gf);
            go = fmaf(wo[k], hk, go);
        }

        if (act_lane) ex[t & 1][w][l] = make_float4(gi, gj, gf, go);
        asm volatile("s_waitcnt lgkmcnt(0)" ::: "memory");
        __builtin_amdgcn_s_barrier();
        const float4 op = ex[t & 1][w ^ 1][u];

        const float ai = gi + op.x + cpi + bi0;
        const float aj = gj + op.y + cpj + bj0;
        const float af = gf + op.z + cpf + bf0;
        const float ao = go + op.w + cpo + bo0;

        c = c * sigm(af) + sigm(ai) * tanh_f(aj);
        h = tanh_f(c) * sigm(ao);
    }

    if (w == 0 && act_lane) feat[b * (2 * HID) + l] = h;
}

// ---------------------------------------------------------------------------
// K3: backward LSTM = ONE step (zero init state), fused with BN + MLP head.
// ---------------------------------------------------------------------------
__global__ __launch_bounds__(256) void bw_mlp(const int* __restrict__ x2,
                                              const float* __restrict__ E,
                                              const float* __restrict__ Wbw,
                                              const float* __restrict__ bbw,
                                              const float* __restrict__ W1,
                                              const float* __restrict__ b1,
                                              const float* __restrict__ W2,
                                              const float* __restrict__ b2,
                                              const float* __restrict__ featfw,
                                              float* __restrict__ out) {
    const int b = blockIdx.x;
    const int t = threadIdx.x;

    __shared__ __align__(16) float sx[EMB + 4];
    __shared__ float sf[2 * HID];
    __shared__ float sg[GATES];
    __shared__ float sh1[25];

    const int tok = x2[b * 128 + 127];   // xs[T-1] token
    for (int e = t; e < EMB; e += 256) sx[e] = E[(size_t)tok * EMB + e];
    if (t < HID) sf[t] = featfw[b * (2 * HID) + t];
    __syncthreads();

    if (t < GATES) {
        float g0 = bbw[t], g1 = 0.0f, g2 = 0.0f, g3 = 0.0f;
        for (int e = 0; e < EMB; e += 4) {
            g0 = fmaf(sx[e + 0], Wbw[(e + 0) * GATES + t], g0);
            g1 = fmaf(sx[e + 1], Wbw[(e + 1) * GATES + t], g1);
            g2 = fmaf(sx[e + 2], Wbw[(e + 2) * GATES + t], g2);
            g3 = fmaf(sx[e + 3], Wbw[(e + 3) * GATES + t], g3);
        }
        sg[t] = (g0 + g1) + (g2 + g3);
    }
    __syncthreads();

    if (t < HID) {
        const float c2 = sigm(sg[t]) * tanh_f(sg[t + HID]);
        sf[HID + t] = tanh_f(c2) * sigm(sg[t + 3 * HID]);
    }
    __syncthreads();

    if (t < 25) {
        float a = 0.0f;
#pragma unroll 4
        for (int k = 0; k < 2 * HID; ++k)
            a = fmaf(sf[k], W1[k * 25 + t], a);
        a = fmaf(a, BN_SCALE, b1[t]);
        sh1[t] = fmaxf(a, 0.0f);
    }
    __syncthreads();

    if (t < 3) {
        float a = b2[t];
#pragma unroll
        for (int k = 0; k < 25; ++k)
            a = fmaf(sh1[k], W2[k * 3 + t], a);
        out[b * 3 + t] = a * BN_SCALE;
    }
}

// ---------------------------------------------------------------------------
extern "C" void kernel_launch(void* const* d_in, const int* in_sizes, int n_in,
                              void* d_out, int out_size, void* d_ws, size_t ws_size,
                              hipStream_t stream) {
    const int*   x1  = (const int*)d_in[0];
    const int*   x2  = (const int*)d_in[1];
    const float* E   = (const float*)d_in[2];
    const float* Wfw = (const float*)d_in[3];
    const float* bfw = (const float*)d_in[4];
    const float* Wbw = (const float*)d_in[5];
    const float* bbw = (const float*)d_in[6];
    const float* W1  = (const float*)d_in[7];
    const float* b1  = (const float*)d_in[8];
    const float* W2  = (const float*)d_in[9];
    const float* b2  = (const float*)d_in[10];
    float* out = (float*)d_out;

    // ws layout: P [50000*200] f32 (40 MB) | feat [1024*100] f32 | WhT | WlT
    float* Pm   = (float*)d_ws;
    float* feat = Pm + (size_t)VOCAB * GATES;
    unsigned short* WhT = (unsigned short*)(feat + BATCH * 2 * HID);
    unsigned short* WlT = WhT + (size_t)NPAD * KPAD;

    split_w<<<(NPAD * KPAD + 255) / 256, 256, 0, stream>>>(Wfw, WhT, WlT);
    vocab_proj_mfma<<<(VOCAB + 63) / 64, 256, 0, stream>>>(E, WhT, WlT, Pm);
    lstm_fw<<<BATCH, 128, 0, stream>>>(x1, x2, Pm, Wfw, bfw, feat);
    bw_mlp<<<BATCH, 256, 0, stream>>>(x2, E, Wbw, bbw, W1, b1, W2, b2, feat, out);
}

// Round 5
// 467.971 us; speedup vs baseline: 1.0654x; 1.0654x over previous
//
#include <hip/hip_runtime.h>
#include <hip/hip_bf16.h>

// Network: bidirectional LSTM (T=256, B=1024, E=300, H=50) + small MLP head.
// h_bw[0] needs only ONE backward step (zero init state); x@Wx hoisted into
// per-VOCAB precompute P = E @ W_fw[0:300,:] computed with split-bf16 MFMA.

#define VOCAB 50000
#define EMB   300
#define HID   50
#define GATES 200          // 4*H
#define BATCH 1024
#define TT    256          // 2*MAX_LEN
#define NPAD  208          // 13 * 16
#define KPAD  320          // 10 * 32
#define BN_SCALE 0.9995003746877732f   // 1/sqrt(1.001)

typedef short bf16x8 __attribute__((ext_vector_type(8)));
typedef float f32x4  __attribute__((ext_vector_type(4)));

__device__ __forceinline__ float sigm(float x) {
    return 1.0f / (1.0f + __expf(-x));
}
__device__ __forceinline__ float tanh_f(float x) {
    return 1.0f - 2.0f / (__expf(2.0f * x) + 1.0f);   // saturates correctly
}
__device__ __forceinline__ unsigned short f32_to_bf16(float x) {
    unsigned int u = __float_as_uint(x);
    u += 0x7fffu + ((u >> 16) & 1u);   // round-to-nearest-even (finite inputs)
    return (unsigned short)(u >> 16);
}
__device__ __forceinline__ float bf16_to_f32(unsigned short h) {
    return __uint_as_float(((unsigned int)h) << 16);
}

// ---------------------------------------------------------------------------
// K0: split Wx = W_fw[0:300,:] into bf16 hi/lo, TRANSPOSED + zero-padded to
// [NPAD][KPAD] so B-fragments are contiguous 16B loads. 66560 elems, tiny.
// ---------------------------------------------------------------------------
__global__ __launch_bounds__(256) void split_w(const float* __restrict__ Wfw,
                                               unsigned short* __restrict__ WhT,
                                               unsigned short* __restrict__ WlT) {
    const int idx = blockIdx.x * 256 + threadIdx.x;
    if (idx >= NPAD * KPAD) return;
    const int n = idx / KPAD;
    const int k = idx - n * KPAD;
    float v = (n < GATES && k < EMB) ? Wfw[k * GATES + n] : 0.0f;
    const unsigned short hb = f32_to_bf16(v);
    const unsigned short lb = f32_to_bf16(v - bf16_to_f32(hb));
    WhT[idx] = hb;
    WlT[idx] = lb;
}

// ---------------------------------------------------------------------------
// K1: P = E @ Wx via 16x16x32 bf16 MFMA, error-compensated split:
//     E*W ~= Eh*Wh + El*Wh + Eh*Wl  (f32 accumulate; dropped El*Wl ~ 1e-5).
// 128 rows/block, 4 waves; wave owns TWO 16-row tiles x 208 cols, so each
// B-fragment load (the former VMEM bottleneck) feeds 6 MFMAs instead of 3.
// C/D layout: col = lane&15, row = (lane>>4)*4 + reg   [measured m89/m91]
// ---------------------------------------------------------------------------
__global__ __launch_bounds__(256, 1) void vocab_proj_mfma(const float* __restrict__ E,
                                                          const unsigned short* __restrict__ WhT,
                                                          const unsigned short* __restrict__ WlT,
                                                          float* __restrict__ P) {
    const int w  = threadIdx.x >> 6;
    const int l  = threadIdx.x & 63;
    const int lr = l & 15;        // row-in-tile (A) / col-in-frag (B, C)
    const int lg = l >> 4;        // k-group (A,B) / row-group (C)

    const int row0 = blockIdx.x * 128 + w * 32 + lr;        // tile 0
    const int row1 = row0 + 16;                             // tile 1
    const int rc0  = (row0 < VOCAB) ? row0 : (VOCAB - 1);
    const int rc1  = (row1 < VOCAB) ? row1 : (VOCAB - 1);
    const float* Erow0 = E + (size_t)rc0 * EMB;
    const float* Erow1 = E + (size_t)rc1 * EMB;

    f32x4 acc0[13], acc1[13];
#pragma unroll
    for (int f = 0; f < 13; ++f) {
        acc0[f] = (f32x4){0.f, 0.f, 0.f, 0.f};
        acc1[f] = (f32x4){0.f, 0.f, 0.f, 0.f};
    }

    for (int ks = 0; ks < 10; ++ks) {
        const int k0 = ks * 32 + lg * 8;
        float av0[8], av1[8];
        if (ks < 9) {
            const float4 a00 = *reinterpret_cast<const float4*>(Erow0 + k0);
            const float4 a01 = *reinterpret_cast<const float4*>(Erow0 + k0 + 4);
            const float4 a10 = *reinterpret_cast<const float4*>(Erow1 + k0);
            const float4 a11 = *reinterpret_cast<const float4*>(Erow1 + k0 + 4);
            av0[0]=a00.x; av0[1]=a00.y; av0[2]=a00.z; av0[3]=a00.w;
            av0[4]=a01.x; av0[5]=a01.y; av0[6]=a01.z; av0[7]=a01.w;
            av1[0]=a10.x; av1[1]=a10.y; av1[2]=a10.z; av1[3]=a10.w;
            av1[4]=a11.x; av1[5]=a11.y; av1[6]=a11.z; av1[7]=a11.w;
        } else {
#pragma unroll
            for (int j = 0; j < 8; ++j) {
                const int kk = k0 + j;
                av0[j] = (kk < EMB) ? Erow0[kk] : 0.0f;
                av1[j] = (kk < EMB) ? Erow1[kk] : 0.0f;
            }
        }
        bf16x8 ah0, al0, ah1, al1;
#pragma unroll
        for (int j = 0; j < 8; ++j) {
            unsigned short hb = f32_to_bf16(av0[j]);
            ah0[j] = (short)hb;
            al0[j] = (short)f32_to_bf16(av0[j] - bf16_to_f32(hb));
            hb = f32_to_bf16(av1[j]);
            ah1[j] = (short)hb;
            al1[j] = (short)f32_to_bf16(av1[j] - bf16_to_f32(hb));
        }

#pragma unroll
        for (int f = 0; f < 13; ++f) {
            const int n = f * 16 + lr;
            const size_t boff = (size_t)n * KPAD + k0;
            const bf16x8 bh = *reinterpret_cast<const bf16x8*>(WhT + boff);
            const bf16x8 bl = *reinterpret_cast<const bf16x8*>(WlT + boff);
            acc0[f] = __builtin_amdgcn_mfma_f32_16x16x32_bf16(ah0, bh, acc0[f], 0, 0, 0);
            acc0[f] = __builtin_amdgcn_mfma_f32_16x16x32_bf16(al0, bh, acc0[f], 0, 0, 0);
            acc0[f] = __builtin_amdgcn_mfma_f32_16x16x32_bf16(ah0, bl, acc0[f], 0, 0, 0);
            acc1[f] = __builtin_amdgcn_mfma_f32_16x16x32_bf16(ah1, bh, acc1[f], 0, 0, 0);
            acc1[f] = __builtin_amdgcn_mfma_f32_16x16x32_bf16(al1, bh, acc1[f], 0, 0, 0);
            acc1[f] = __builtin_amdgcn_mfma_f32_16x16x32_bf16(ah1, bl, acc1[f], 0, 0, 0);
        }
    }

    const int or0 = blockIdx.x * 128 + w * 32 + lg * 4;
#pragma unroll
    for (int f = 0; f < 13; ++f) {
        const int col = f * 16 + lr;
        if (col < GATES) {
#pragma unroll
            for (int r = 0; r < 4; ++r) {
                const int oa = or0 + r;
                const int ob = oa + 16;
                if (oa < VOCAB) P[(size_t)oa * GATES + col] = acc0[f][r];
                if (ob < VOCAB) P[(size_t)ob * GATES + col] = acc1[f][r];
            }
        }
    }
}

// ---------------------------------------------------------------------------
// K2: forward LSTM. 2 waves per batch row, split along K: wave w accumulates
// k in [25w, 25w+25) for ALL FOUR gate columns of its lane's unit (100 weight
// VGPRs). The weights are PINNED with an empty asm "+v" after loading --
// this makes the values opaque so the compiler CANNOT rematerialize the
// global loads inside the step loop (R3/R4 failure mode: VGPR_Count 60/80
// meant ~100 reloads/step). Partials exchanged once/step (float4, parity
// double-buffer, raw s_barrier + lgkmcnt-only drain); both waves redundantly
// compute activations and c,h. P-row prefetch stays in flight across the
// barrier (no vmcnt drain).
// ---------------------------------------------------------------------------
__global__ __launch_bounds__(128, 1) void lstm_fw(const int* __restrict__ x1,
                                                  const int* __restrict__ x2,
                                                  const float* __restrict__ P,
                                                  const float* __restrict__ Wfw,
                                                  const float* __restrict__ bfw,
                                                  float* __restrict__ feat) {
    const int b = blockIdx.x;
    const int w = threadIdx.x >> 6;      // k-half owner
    const int l = threadIdx.x & 63;
    const int u = (l < HID) ? l : (HID - 1);   // clamp for loads
    const bool act_lane = (l < HID);

    __shared__ int    stok[TT];
    __shared__ float4 ex[2][2][HID];     // [parity][wave][unit] partial gates

    stok[threadIdx.x]       = x1[b * 128 + threadIdx.x];
    stok[128 + threadIdx.x] = x2[b * 128 + threadIdx.x];

    // weights for k-range [25w, 25w+25), all 4 gate columns of unit u
    float wi[25], wj[25], wf[25], wo[25];
#pragma unroll
    for (int k = 0; k < 25; ++k) {
        const float* rowp = Wfw + (size_t)(EMB + 25 * w + k) * GATES;
        wi[k] = rowp[u];
        wj[k] = rowp[u + 50];
        wf[k] = rowp[u + 100];
        wo[k] = rowp[u + 150];
    }
    // PIN: make weight values opaque -> no remat of the loads in the loop.
#pragma unroll
    for (int k = 0; k < 25; ++k) {
        asm volatile("" : "+v"(wi[k]), "+v"(wj[k]), "+v"(wf[k]), "+v"(wo[k]));
    }

    const float bi0 = bfw[u];
    const float bj0 = bfw[u + 50];
    const float bf0 = bfw[u + 100] + 1.0f;   // forget_bias folded in
    const float bo0 = bfw[u + 150];

    float c = 0.0f, h = 0.0f;
    __syncthreads();   // tokens staged (once)

    int tok = stok[0];
    const float* pr0 = P + (size_t)tok * GATES + u;
    float pi = pr0[0], pj = pr0[50], pf = pr0[100], po = pr0[150];
    int tokn = stok[1];

    for (int t = 0; t < TT; ++t) {
        const float cpi = pi, cpj = pj, cpf = pf, cpo = po;
        // prefetch step t+1 (stays in flight across the s_barrier)
        {
            const float* pn = P + (size_t)tokn * GATES + u;
            pi = pn[0]; pj = pn[50]; pf = pn[100]; po = pn[150];
        }
        tokn = stok[(t + 2 < TT) ? (t + 2) : (TT - 1)];

        float gi = 0.0f, gj = 0.0f, gf = 0.0f, go = 0.0f;
#pragma unroll
        for (int k = 0; k < 25; ++k) {
            const float hk = __uint_as_float(
                __builtin_amdgcn_readlane(__float_as_uint(h), 25 * w + k));
            gi = fmaf(wi[k], hk, gi);
            gj = fmaf(wj[k], hk, gj);
            gf = fmaf(wf[k], hk, gf);
            go = fmaf(wo[k], hk, go);
        }

        if (act_lane) ex[t & 1][w][l] = make_float4(gi, gj, gf, go);
        asm volatile("s_waitcnt lgkmcnt(0)" ::: "memory");
        __builtin_amdgcn_s_barrier();
        const float4 op = ex[t & 1][w ^ 1][u];

        const float ai = gi + op.x + cpi + bi0;
        const float aj = gj + op.y + cpj + bj0;
        const float af = gf + op.z + cpf + bf0;
        const float ao = go + op.w + cpo + bo0;

        c = c * sigm(af) + sigm(ai) * tanh_f(aj);
        h = tanh_f(c) * sigm(ao);
    }

    if (w == 0 && act_lane) feat[b * (2 * HID) + l] = h;
}

// ---------------------------------------------------------------------------
// K3: backward LSTM = ONE step (zero init state), fused with BN + MLP head.
// ---------------------------------------------------------------------------
__global__ __launch_bounds__(256) void bw_mlp(const int* __restrict__ x2,
                                              const float* __restrict__ E,
                                              const float* __restrict__ Wbw,
                                              const float* __restrict__ bbw,
                                              const float* __restrict__ W1,
                                              const float* __restrict__ b1,
                                              const float* __restrict__ W2,
                                              const float* __restrict__ b2,
                                              const float* __restrict__ featfw,
                                              float* __restrict__ out) {
    const int b = blockIdx.x;
    const int t = threadIdx.x;

    __shared__ __align__(16) float sx[EMB + 4];
    __shared__ float sf[2 * HID];
    __shared__ float sg[GATES];
    __shared__ float sh1[25];

    const int tok = x2[b * 128 + 127];   // xs[T-1] token
    for (int e = t; e < EMB; e += 256) sx[e] = E[(size_t)tok * EMB + e];
    if (t < HID) sf[t] = featfw[b * (2 * HID) + t];
    __syncthreads();

    if (t < GATES) {
        float g0 = bbw[t], g1 = 0.0f, g2 = 0.0f, g3 = 0.0f;
        for (int e = 0; e < EMB; e += 4) {
            g0 = fmaf(sx[e + 0], Wbw[(e + 0) * GATES + t], g0);
            g1 = fmaf(sx[e + 1], Wbw[(e + 1) * GATES + t], g1);
            g2 = fmaf(sx[e + 2], Wbw[(e + 2) * GATES + t], g2);
            g3 = fmaf(sx[e + 3], Wbw[(e + 3) * GATES + t], g3);
        }
        sg[t] = (g0 + g1) + (g2 + g3);
    }
    __syncthreads();

    if (t < HID) {
        const float c2 = sigm(sg[t]) * tanh_f(sg[t + HID]);
        sf[HID + t] = tanh_f(c2) * sigm(sg[t + 3 * HID]);
    }
    __syncthreads();

    if (t < 25) {
        float a = 0.0f;
#pragma unroll 4
        for (int k = 0; k < 2 * HID; ++k)
            a = fmaf(sf[k], W1[k * 25 + t], a);
        a = fmaf(a, BN_SCALE, b1[t]);
        sh1[t] = fmaxf(a, 0.0f);
    }
    __syncthreads();

    if (t < 3) {
        float a = b2[t];
#pragma unroll
        for (int k = 0; k < 25; ++k)
            a = fmaf(sh1[k], W2[k * 3 + t], a);
        out[b * 3 + t] = a * BN_SCALE;
    }
}

// ---------------------------------------------------------------------------
extern "C" void kernel_launch(void* const* d_in, const int* in_sizes, int n_in,
                              void* d_out, int out_size, void* d_ws, size_t ws_size,
                              hipStream_t stream) {
    const int*   x1  = (const int*)d_in[0];
    const int*   x2  = (const int*)d_in[1];
    const float* E   = (const float*)d_in[2];
    const float* Wfw = (const float*)d_in[3];
    const float* bfw = (const float*)d_in[4];
    const float* Wbw = (const float*)d_in[5];
    const float* bbw = (const float*)d_in[6];
    const float* W1  = (const float*)d_in[7];
    const float* b1  = (const float*)d_in[8];
    const float* W2  = (const float*)d_in[9];
    const float* b2  = (const float*)d_in[10];
    float* out = (float*)d_out;

    // ws layout: P [50000*200] f32 (40 MB) | feat [1024*100] f32 | WhT | WlT
    float* Pm   = (float*)d_ws;
    float* feat = Pm + (size_t)VOCAB * GATES;
    unsigned short* WhT = (unsigned short*)(feat + BATCH * 2 * HID);
    unsigned short* WlT = WhT + (size_t)NPAD * KPAD;

    split_w<<<(NPAD * KPAD + 255) / 256, 256, 0, stream>>>(Wfw, WhT, WlT);
    vocab_proj_mfma<<<(VOCAB + 127) / 128, 256, 0, stream>>>(E, WhT, WlT, Pm);
    lstm_fw<<<BATCH, 128, 0, stream>>>(x1, x2, Pm, Wfw, bfw, feat);
    bw_mlp<<<BATCH, 256, 0, stream>>>(x2, E, Wbw, bbw, W1, b1, W2, b2, feat, out);
}